// Round 9
// baseline (45612.192 us; speedup 1.0000x reference)
//
#include <hip/hip_runtime.h>

typedef __attribute__((ext_vector_type(8))) short short8;
typedef __attribute__((ext_vector_type(4))) float f32x4;
typedef __attribute__((ext_vector_type(4))) unsigned int u32x4;
typedef unsigned short u16;
typedef unsigned int u32;

#define T_LEN 512
#define BATCH 64
#define HID 400
#define GATES 1200
#define DIN 800

// workspace offsets (bytes)
#define R0_OFF   0ull                          // 104,857,600
#define R1_OFF   104857600ull                  // 104,857,600
#define WX_OFF   209715200ull                  // [2][1200][800] bf16 = 3,840,000
#define WHF_OFF  213555200ull                  // [2][25][3][13][64][8] bf16 = 3,993,600
#define HST_OFF  217548800ull                  // [2][4][16][416] bf16 = 106,496
#define CST_OFF  217655296ull                  // [2][4][16][400] f32 = 204,800
#define GX_OFF   217860096ull                  // [2][CH][64][1200] bf16

__device__ __forceinline__ u16 f2bf(float f) {
    u32 u = __builtin_bit_cast(u32, f);
    u += 0x7fffu + ((u >> 16) & 1u);
    return (u16)(u >> 16);
}
__device__ __forceinline__ float bfhi(u32 d) { return __builtin_bit_cast(float, d & 0xFFFF0000u); }
__device__ __forceinline__ float bflo(u32 d) { return __builtin_bit_cast(float, d << 16); }
__device__ __forceinline__ float sigf(float x) { return 1.f / (1.f + __expf(-x)); }
__device__ __forceinline__ float tanhf_(float x) { return 1.f - 2.f / (__expf(2.f * x) + 1.f); }
__device__ __forceinline__ u32 cvtpk(float a, float b) {
    u32 r; asm("v_cvt_pk_bf16_f32 %0, %1, %2" : "=v"(r) : "v"(a), "v"(b)); return r;
}
__device__ __forceinline__ short8 cvt8(const float* p) {
    float4 u = *(const float4*)p, v = *(const float4*)(p + 4);
    u32x4 w = {cvtpk(u.x, u.y), cvtpk(u.z, u.w), cvtpk(v.x, v.y), cvtpk(v.z, v.w)};
    return __builtin_bit_cast(short8, w);
}

// ---- Wx: [2][1200][800] bf16 (x-part of W) ----
__global__ void cast_Wx(const float* __restrict__ fW, const float* __restrict__ bW,
                        u16* __restrict__ Wx, int layer) {
    const int n = 2 * GATES * DIN;
    for (int i = blockIdx.x * blockDim.x + threadIdx.x; i < n; i += gridDim.x * blockDim.x) {
        int d = i / (GATES * DIN);
        int rem = i - d * (GATES * DIN);
        int r = rem / DIN, k = rem - (rem / DIN) * DIN;
        const float* src = (d ? bW : fW);
        Wx[i] = f2bf(src[((size_t)layer * GATES + r) * 1200 + k]);
    }
}

// ---- Whf: [2][25 tr][3 g][13 k][64 lane][8] bf16 A-fragments of Wh ----
__global__ void cast_Whf(const float* __restrict__ fW, const float* __restrict__ bW,
                         u16* __restrict__ Whf, int layer) {
    const int n = 2 * 25 * 3 * 13 * 64 * 8;
    for (int i = blockIdx.x * blockDim.x + threadIdx.x; i < n; i += gridDim.x * blockDim.x) {
        int e = i & 7, lane = (i >> 3) & 63;
        int r = i >> 9;             // [dir][tr][g][k]
        int k = r % 13; r /= 13;
        int g = r % 3;  r /= 3;
        int tr = r % 25; int d = r / 25;
        int grow = g * HID + tr * 16 + (lane & 15);
        int kcol = k * 32 + (lane >> 4) * 8 + e;
        const float* src = (d ? bW : fW);
        Whf[i] = (kcol < HID) ? f2bf(src[((size_t)layer * GATES + grow) * 1200 + DIN + kcol]) : (u16)0;
    }
}

// ---- xgemm: Gx[dir][tc][b][n] = bf16( inp[t(b,tc)] @ Wx^T + bias ) ----
__global__ __launch_bounds__(256) void xgemm(
    const float* __restrict__ inp,  // [T*B, 800] f32
    const u16* __restrict__ Wx,     // [2][1200][800]
    const float* __restrict__ fb_l, const float* __restrict__ bb_l,
    u16* __restrict__ Gx, int tch0, int CH)
{
    const int dir = blockIdx.z;
    const int m0 = blockIdx.x * 128, n0 = blockIdx.y * 128;
    const int tid = threadIdx.x, lane = tid & 63, wave = tid >> 6;
    const int wy = wave >> 1, wxw = wave & 1;
    const int l15 = lane & 15, hi = lane >> 4;
    const u16* Bw = Wx + (size_t)dir * GATES * DIN;
    const float* bias = dir ? bb_l : fb_l;
    const short8 zero8 = {};

    const int arow0 = m0 + wy * 64 + l15;
    const int brow0 = n0 + wxw * 64 + l15;

    // A row pointers (t mapping): per mf, tc is uniform across l15
    const float* ap[4];
#pragma unroll
    for (int mf = 0; mf < 4; ++mf) {
        int rowc = arow0 + mf * 16;
        int tc = rowc >> 6, b = rowc & 63;
        int t = dir ? (T_LEN - 1 - (tch0 + tc)) : (tch0 + tc);
        ap[mf] = inp + ((size_t)t * BATCH + b) * DIN;
    }
    float bv[4];
#pragma unroll
    for (int nf = 0; nf < 4; ++nf) {
        int bn = brow0 + nf * 16 - l15 + l15; // = n0 + wxw*64 + nf*16 + l15
        bv[nf] = (bn < GATES) ? bias[bn] : 0.f;
    }
    f32x4 acc[4][4];
#pragma unroll
    for (int mf = 0; mf < 4; ++mf)
#pragma unroll
        for (int nf = 0; nf < 4; ++nf)
#pragma unroll
            for (int j = 0; j < 4; ++j) acc[mf][nf][j] = bv[nf];

    for (int kk = 0; kk < 25; ++kk) {
        const int k0 = kk * 32 + 8 * hi;
        short8 a[4], b[4];
#pragma unroll
        for (int mf = 0; mf < 4; ++mf) a[mf] = cvt8(ap[mf] + k0);
#pragma unroll
        for (int nf = 0; nf < 4; ++nf) {
            int br = brow0 + nf * 16;
            b[nf] = (br < GATES) ? *(const short8*)(Bw + (size_t)br * DIN + k0) : zero8;
        }
#pragma unroll
        for (int mf = 0; mf < 4; ++mf)
#pragma unroll
            for (int nf = 0; nf < 4; ++nf)
                acc[mf][nf] = __builtin_amdgcn_mfma_f32_16x16x32_bf16(a[mf], b[nf], acc[mf][nf], 0, 0, 0);
    }

#pragma unroll
    for (int mf = 0; mf < 4; ++mf)
#pragma unroll
        for (int nf = 0; nf < 4; ++nf)
#pragma unroll
            for (int j = 0; j < 4; ++j) {
                int rowc = m0 + wy * 64 + mf * 16 + hi * 4 + j;
                int n = n0 + wxw * 64 + nf * 16 + l15;
                if (n < GATES) {
                    int tc = rowc >> 6, b = rowc & 63;
                    Gx[(((size_t)dir * CH + tc) * BATCH + b) * GATES + n] = f2bf(acc[mf][nf][j]);
                }
            }
}

// ---- persistent recurrent kernel: 8 blocks (2 dir x 4 quarters), 1024 threads ----
// Gate GEMM transposed: C[gate-row][batch]; each wave holds the (i,j,o) triples for its
// 16-column groups in REGISTERS (W A-frags), h in LDS (B-frags). Cell fully in-register.
#define CELL_COMPUTE(ACC, GXA, C4, HN)                                           \
    do {                                                                         \
        _Pragma("unroll")                                                        \
        for (int j = 0; j < 4; ++j) {                                            \
            u32 di = (j < 2) ? GXA[0].x : GXA[0].y;                              \
            u32 dj = (j < 2) ? GXA[1].x : GXA[1].y;                              \
            u32 dd = (j < 2) ? GXA[2].x : GXA[2].y;                              \
            float pi = ACC[0][j] + ((j & 1) ? bfhi(di) : bflo(di));              \
            float pj = ACC[1][j] + ((j & 1) ? bfhi(dj) : bflo(dj));              \
            float po = ACC[2][j] + ((j & 1) ? bfhi(dd) : bflo(dd));              \
            float ig = sigf(pi), jg = tanhf_(pj), og = sigf(po);                 \
            float cn = m * ((1.f - ig) * C4[j] + ig * jg);                       \
            C4[j] = cn;                                                          \
            HN[j] = m * (tanhf_(cn) * og);                                       \
        }                                                                        \
    } while (0)

__global__ __launch_bounds__(1024) void recur(
    const u16* __restrict__ Gx,     // [2][CH][64][1200]
    const u16* __restrict__ Whf,    // [2][25][3][13][64][8]
    const float* __restrict__ masks,// [T*B]
    const float* __restrict__ finit,// [2][400] layer slice
    const float* __restrict__ binit,
    u16* __restrict__ h_st,         // [2][4][16][416]
    float* __restrict__ c_st,       // [2][4][16][400]
    float* __restrict__ raw,        // [T*B, 800]
    int tch0, int CH, int first)
{
    const int dir = blockIdx.x >> 2, bq = blockIdx.x & 3;
    const int tid = threadIdx.x, wave = tid >> 6, lane = tid & 63;
    const int l15 = lane & 15, hi = lane >> 4;
    const bool two = (wave < 9);
    const int tr0 = two ? 2 * wave : 9 + wave;
    const int tr1 = two ? tr0 + 1 : tr0;
    const int c00 = tr0 * 16 + hi * 4;
    const int c01 = tr1 * 16 + hi * 4;

    __shared__ u16 hlds[16 * 424];   // row stride 424 halves (848B): conflict-free b128 pattern

    // ---- load W fragments into registers ----
    short8 wf0[3][13], wf1[3][13];
#pragma unroll
    for (int g = 0; g < 3; ++g)
#pragma unroll
        for (int k = 0; k < 13; ++k)
            wf0[g][k] = *(const short8*)(Whf + ((((size_t)dir * 25 + tr0) * 3 + g) * 13 + k) * 512 + lane * 8);
    if (two) {
#pragma unroll
        for (int g = 0; g < 3; ++g)
#pragma unroll
            for (int k = 0; k < 13; ++k)
                wf1[g][k] = *(const short8*)(Whf + ((((size_t)dir * 25 + tr1) * 3 + g) * 13 + k) * 512 + lane * 8);
    }

    // ---- init h (LDS) and c (registers) ----
    float c40[4], c41[4];
    if (first) {
        const float* ini = dir ? binit : finit;
        for (int i = tid; i < 16 * 424; i += 1024) {
            int col = i % 424;
            hlds[i] = (col < HID) ? f2bf(ini[col]) : (u16)0;
        }
#pragma unroll
        for (int j = 0; j < 4; ++j) {
            c40[j] = ini[HID + c00 + j];
            c41[j] = ini[HID + c01 + j];
        }
    } else {
        const u16* hs = h_st + ((size_t)(dir * 4 + bq) * 16) * 416;
        for (int i = tid; i < 16 * 416; i += 1024) {
            int b = i / 416, col = i - b * 416;
            hlds[b * 424 + col] = hs[i];
        }
        const float* cs = c_st + ((size_t)(dir * 4 + bq) * 16 + l15) * HID;
        f32x4 cv0 = *(const f32x4*)(cs + c00);
        f32x4 cv1 = *(const f32x4*)(cs + c01);
#pragma unroll
        for (int j = 0; j < 4; ++j) { c40[j] = cv0[j]; c41[j] = cv1[j]; }
    }
    __syncthreads();

    const u16* gp0 = Gx + (((size_t)dir * CH) * BATCH + bq * 16 + l15) * GATES;

    for (int tc = 0; tc < CH; ++tc) {
        const int tf = tch0 + tc;
        const int t = dir ? (T_LEN - 1 - tf) : tf;

        // Gx loads for this step (consumed after the k-loop -> latency hidden)
        const u16* gp = gp0 + (size_t)tc * BATCH * GATES;
        uint2 gx0[3], gx1[3];
#pragma unroll
        for (int g = 0; g < 3; ++g) {
            gx0[g] = *(const uint2*)(gp + g * HID + c00);
            if (two) gx1[g] = *(const uint2*)(gp + g * HID + c01);
        }
        const float m = masks[t * BATCH + bq * 16 + l15];

        // ---- MFMA k-loop: h B-frags from LDS x W A-frags from registers ----
        f32x4 acc0[3] = {}, acc1[3] = {};
        if (two) {
#pragma unroll
            for (int k = 0; k < 13; ++k) {
                short8 hb = *(const short8*)&hlds[l15 * 424 + k * 32 + hi * 8];
#pragma unroll
                for (int g = 0; g < 3; ++g)
                    acc0[g] = __builtin_amdgcn_mfma_f32_16x16x32_bf16(wf0[g][k], hb, acc0[g], 0, 0, 0);
#pragma unroll
                for (int g = 0; g < 3; ++g)
                    acc1[g] = __builtin_amdgcn_mfma_f32_16x16x32_bf16(wf1[g][k], hb, acc1[g], 0, 0, 0);
            }
        } else {
#pragma unroll
            for (int k = 0; k < 13; ++k) {
                short8 hb = *(const short8*)&hlds[l15 * 424 + k * 32 + hi * 8];
#pragma unroll
                for (int g = 0; g < 3; ++g)
                    acc0[g] = __builtin_amdgcn_mfma_f32_16x16x32_bf16(wf0[g][k], hb, acc0[g], 0, 0, 0);
            }
        }

        // ---- cell (register-local) ----
        float hn0[4], hn1[4];
        CELL_COMPUTE(acc0, gx0, c40, hn0);
        if (two) CELL_COMPUTE(acc1, gx1, c41, hn1);

        __syncthreads();   // all waves done reading hlds
        {
            uint2 hp; hp.x = cvtpk(hn0[0], hn0[1]); hp.y = cvtpk(hn0[2], hn0[3]);
            *(uint2*)&hlds[l15 * 424 + c00] = hp;
            float4 rv = make_float4(hn0[0], hn0[1], hn0[2], hn0[3]);
            *(float4*)(raw + ((size_t)t * BATCH + bq * 16 + l15) * (2 * HID) + dir * HID + c00) = rv;
        }
        if (two) {
            uint2 hp; hp.x = cvtpk(hn1[0], hn1[1]); hp.y = cvtpk(hn1[2], hn1[3]);
            *(uint2*)&hlds[l15 * 424 + c01] = hp;
            float4 rv = make_float4(hn1[0], hn1[1], hn1[2], hn1[3]);
            *(float4*)(raw + ((size_t)t * BATCH + bq * 16 + l15) * (2 * HID) + dir * HID + c01) = rv;
        }
        __syncthreads();   // new h visible to all waves
    }

    // ---- chunk-end state dump ----
    {
        float* cs = c_st + ((size_t)(dir * 4 + bq) * 16 + l15) * HID;
        float4 cv0 = make_float4(c40[0], c40[1], c40[2], c40[3]);
        *(float4*)(cs + c00) = cv0;
        if (two) {
            float4 cv1 = make_float4(c41[0], c41[1], c41[2], c41[3]);
            *(float4*)(cs + c01) = cv1;
        }
    }
    u16* hs = h_st + ((size_t)(dir * 4 + bq) * 16) * 416;
    for (int i = tid; i < 16 * 416; i += 1024) {
        int b = i / 416, col = i - b * 416;
        hs[i] = hlds[b * 424 + col];
    }
}

// ---- save final h/c states ----
__global__ void save_states(const float* __restrict__ raw, const float* __restrict__ c_st,
                            float* __restrict__ out, int layer) {
    const int n = 2 * BATCH * HID;
    for (int i = blockIdx.x * blockDim.x + threadIdx.x; i < n; i += gridDim.x * blockDim.x) {
        int d = i / (BATCH * HID);
        int rem = i - d * (BATCH * HID);
        int b = rem / HID, k = rem - (rem / HID) * HID;
        int t = d ? 0 : (T_LEN - 1);
        float h = raw[((size_t)t * BATCH + b) * (2 * HID) + d * HID + k];
        float c = c_st[((size_t)(d * 4 + (b >> 4)) * 16 + (b & 15)) * HID + k];
        size_t base = (size_t)T_LEN * BATCH * (2 * HID);
        size_t idx = ((size_t)(2 * layer + d) * BATCH + b) * HID + k;
        out[base + idx] = h;
        out[base + (size_t)2 * 3 * BATCH * HID + idx] = c;
    }
}

// ---- highway pass 1: gates = sigmoid(raw_half @ pW^T + pb) -> Gbuf bf16 ----
__global__ __launch_bounds__(256) void hw_gemm(
    const float* __restrict__ A,    // raw half: [16384][800] f32
    const float* __restrict__ Bw,   // pW slice [800][800] f32
    const float* __restrict__ pb,
    u16* __restrict__ Gbuf)         // [16384][800]
{
    const int m0 = blockIdx.x * 128, n0 = blockIdx.y * 128;
    const int tid = threadIdx.x, lane = tid & 63, wave = tid >> 6;
    const int wy = wave >> 1, wxw = wave & 1;
    const int l15 = lane & 15, hi = lane >> 4;
    const short8 zero8 = {};

    f32x4 acc[4][4] = {};
    const int arow0 = m0 + wy * 64 + l15;
    const int brow0 = n0 + wxw * 64 + l15;

    for (int kk = 0; kk < 25; ++kk) {
        const int k0 = kk * 32 + 8 * hi;
        short8 a[4], b[4];
#pragma unroll
        for (int mf = 0; mf < 4; ++mf)
            a[mf] = cvt8(A + (size_t)(arow0 + mf * 16) * DIN + k0);
#pragma unroll
        for (int nf = 0; nf < 4; ++nf) {
            int br = brow0 + nf * 16;
            b[nf] = (br < DIN) ? cvt8(Bw + (size_t)br * DIN + k0) : zero8;
        }
#pragma unroll
        for (int mf = 0; mf < 4; ++mf)
#pragma unroll
            for (int nf = 0; nf < 4; ++nf)
                acc[mf][nf] = __builtin_amdgcn_mfma_f32_16x16x32_bf16(a[mf], b[nf], acc[mf][nf], 0, 0, 0);
    }
#pragma unroll
    for (int mf = 0; mf < 4; ++mf)
#pragma unroll
        for (int nf = 0; nf < 4; ++nf)
#pragma unroll
            for (int j = 0; j < 4; ++j) {
                int row = m0 + wy * 64 + mf * 16 + hi * 4 + j;
                int col = n0 + wxw * 64 + nf * 16 + l15;
                if (col < DIN)
                    Gbuf[(size_t)row * DIN + col] = f2bf(sigf(acc[mf][nf][j] + pb[col]));
            }
}

// ---- highway pass 2: raw = g*raw + (1-g)*inp on rows [mb, mb+16384) ----
__global__ void hw_blend(float* __restrict__ raw, const float* __restrict__ inp,
                         const u16* __restrict__ Gbuf, int mb) {
    const int n4 = 16384 * DIN / 4;
    const size_t base = (size_t)mb * DIN;
    for (int i = blockIdx.x * blockDim.x + threadIdx.x; i < n4; i += gridDim.x * blockDim.x) {
        size_t off = base + (size_t)i * 4;
        float4 r = *(const float4*)(raw + off);
        float4 p = *(const float4*)(inp + off);
        uint2 gg = *(const uint2*)(Gbuf + (size_t)i * 4);
        float g0 = bflo(gg.x), g1 = bfhi(gg.x), g2 = bflo(gg.y), g3 = bfhi(gg.y);
        r.x = g0 * r.x + (1.f - g0) * p.x;
        r.y = g1 * r.y + (1.f - g1) * p.y;
        r.z = g2 * r.z + (1.f - g2) * p.z;
        r.w = g3 * r.w + (1.f - g3) * p.w;
        *(float4*)(raw + off) = r;
    }
}

// ---------------- host ----------------
extern "C" void kernel_launch(void* const* d_in, const int* in_sizes, int n_in,
                              void* d_out, int out_size, void* d_ws, size_t ws_size,
                              hipStream_t stream) {
    const float* x      = (const float*)d_in[0];
    const float* masks  = (const float*)d_in[1];
    const float* fW     = (const float*)d_in[2];
    const float* fb     = (const float*)d_in[3];
    const float* bW     = (const float*)d_in[4];
    const float* bb     = (const float*)d_in[5];
    const float* f_init = (const float*)d_in[6];
    const float* b_init = (const float*)d_in[7];
    const float* pW     = (const float*)d_in[8];
    const float* pb     = (const float*)d_in[9];
    float* out = (float*)d_out;

    char* ws = (char*)d_ws;
    float* R0  = (float*)(ws + R0_OFF);
    float* R1  = (float*)(ws + R1_OFF);
    u16* Wx    = (u16*)(ws + WX_OFF);
    u16* Whf   = (u16*)(ws + WHF_OFF);
    u16* h_st  = (u16*)(ws + HST_OFF);
    float* c_st = (float*)(ws + CST_OFF);
    u16* Gx    = (u16*)(ws + GX_OFF);

    const size_t need512 = GX_OFF + (size_t)2 * 512 * BATCH * GATES * 2;
    const int CH = (ws_size >= need512) ? 512 : 128;
    const int NCH = T_LEN / CH;

    for (int layer = 0; layer < 3; ++layer) {
        float* raw = (layer == 0) ? R0 : (layer == 1) ? R1 : out;
        const float* inp = (layer == 0) ? x : (layer == 1) ? R0 : R1;

        cast_Wx<<<2048, 256, 0, stream>>>(fW, bW, Wx, layer);
        cast_Whf<<<2048, 256, 0, stream>>>(fW, bW, Whf, layer);

        for (int ch = 0; ch < NCH; ++ch) {
            xgemm<<<dim3(CH / 2, 10, 2), 256, 0, stream>>>(
                inp, Wx, fb + layer * GATES, bb + layer * GATES, Gx, ch * CH, CH);
            recur<<<8, 1024, 0, stream>>>(
                Gx, Whf, masks, f_init + layer * 2 * HID, b_init + layer * 2 * HID,
                h_st, c_st, raw, ch * CH, CH, ch == 0);
        }

        save_states<<<200, 256, 0, stream>>>(raw, c_st, out, layer);

        if (layer > 0) {
            const float* pWl = pW + (size_t)(layer - 1) * DIN * DIN;
            const float* pbl = pb + (size_t)(layer - 1) * DIN;
            u16* Gbuf = Gx;   // Gx dead after recur of this layer
            for (int half = 0; half < 2; ++half) {
                hw_gemm<<<dim3(128, 7), 256, 0, stream>>>(
                    raw + (size_t)half * 16384 * DIN, pWl, pbl, Gbuf);
                hw_blend<<<2048, 256, 0, stream>>>(raw, inp, Gbuf, half * 16384);
            }
        }
    }
}

// Round 10
// 6636.785 us; speedup vs baseline: 6.8726x; 6.8726x over previous
//
#include <hip/hip_runtime.h>

typedef __attribute__((ext_vector_type(8))) short short8;
typedef __attribute__((ext_vector_type(4))) float f32x4;
typedef unsigned short u16;
typedef unsigned int u32;
typedef unsigned long long u64;

#define T_LEN 512
#define BATCH 64
#define HID 400
#define GATES 1200   // 3*HID
#define DIN 800      // layer input width (D == 2H)
#define KTOT 1200    // DIN + HID
#define WSTRIDE 1216 // K padded to 38*32
#define HSTRIDE 448  // 896B rows = 7 x 128B lines -> no cross-group line sharing
#define NKK 38       // K-slices of 32

// per-layer sync area (ints): FLAGS [8][50][32] | ARR [8][25][32] | TOK [8][25][32] | VOTE [8][25][32]
#define ARR_OFF   12800
#define TOK_OFF   19200
#define VOTE_OFF  25600
#define SYNC_INTS 32000

__device__ __forceinline__ u16 f2bf(float f) {
    u32 u = __builtin_bit_cast(u32, f);
    u += 0x7fffu + ((u >> 16) & 1u);
    return (u16)(u >> 16);
}
__device__ __forceinline__ float sigmoidf_(float x) { return 1.f / (1.f + expf(-x)); }

// ---------------- cast kernels ----------------
__global__ void cast_f32_bf16(const float* __restrict__ in, u16* __restrict__ out, int n) {
    for (int i = blockIdx.x * blockDim.x + threadIdx.x; i < n; i += gridDim.x * blockDim.x)
        out[i] = f2bf(in[i]);
}

// W_bf layout: [2][GATES][WSTRIDE], cols >= 1200 zeroed
__global__ void cast_W(const float* __restrict__ fW, const float* __restrict__ bW,
                       u16* __restrict__ W_bf, int layer) {
    const int n = 2 * GATES * WSTRIDE;
    for (int i = blockIdx.x * blockDim.x + threadIdx.x; i < n; i += gridDim.x * blockDim.x) {
        int d = i / (GATES * WSTRIDE);
        int rem = i - d * (GATES * WSTRIDE);
        int r = rem / WSTRIDE;
        int k = rem - r * WSTRIDE;
        const float* src = (d ? bW : fW) + (size_t)layer * GATES * KTOT;
        W_bf[i] = (k < KTOT) ? f2bf(src[(size_t)r * KTOT + k]) : (u16)0;
    }
}

// h_bf: [2 dirs][2 bufs][BATCH][HSTRIDE]; buf0 = h_init, buf1 = 0, pads zeroed
__global__ void init_states(const float* __restrict__ f_init, const float* __restrict__ b_init,
                            u16* __restrict__ h_bf, int layer) {
    const int n = 2 * 2 * BATCH * HSTRIDE;
    for (int i = blockIdx.x * blockDim.x + threadIdx.x; i < n; i += gridDim.x * blockDim.x) {
        int d = i / (2 * BATCH * HSTRIDE);
        int rem = i - d * (2 * BATCH * HSTRIDE);
        int buf = rem / (BATCH * HSTRIDE);
        int rem2 = rem - buf * (BATCH * HSTRIDE);
        int k = rem2 % HSTRIDE;
        const float* src = (d ? b_init : f_init) + layer * 2 * HID;
        h_bf[i] = (k < HID && buf == 0) ? f2bf(src[k]) : (u16)0;
    }
}

// issue 25 plain 16B loads (x for a step), no wait
__device__ __forceinline__ void load_x25(const u16* p, short8* d) {
    asm volatile(
        "global_load_dwordx4 %0,  %25, off\n\t"
        "global_load_dwordx4 %1,  %25, off offset:64\n\t"
        "global_load_dwordx4 %2,  %25, off offset:128\n\t"
        "global_load_dwordx4 %3,  %25, off offset:192\n\t"
        "global_load_dwordx4 %4,  %25, off offset:256\n\t"
        "global_load_dwordx4 %5,  %25, off offset:320\n\t"
        "global_load_dwordx4 %6,  %25, off offset:384\n\t"
        "global_load_dwordx4 %7,  %25, off offset:448\n\t"
        "global_load_dwordx4 %8,  %25, off offset:512\n\t"
        "global_load_dwordx4 %9,  %25, off offset:576\n\t"
        "global_load_dwordx4 %10, %25, off offset:640\n\t"
        "global_load_dwordx4 %11, %25, off offset:704\n\t"
        "global_load_dwordx4 %12, %25, off offset:768\n\t"
        "global_load_dwordx4 %13, %25, off offset:832\n\t"
        "global_load_dwordx4 %14, %25, off offset:896\n\t"
        "global_load_dwordx4 %15, %25, off offset:960\n\t"
        "global_load_dwordx4 %16, %25, off offset:1024\n\t"
        "global_load_dwordx4 %17, %25, off offset:1088\n\t"
        "global_load_dwordx4 %18, %25, off offset:1152\n\t"
        "global_load_dwordx4 %19, %25, off offset:1216\n\t"
        "global_load_dwordx4 %20, %25, off offset:1280\n\t"
        "global_load_dwordx4 %21, %25, off offset:1344\n\t"
        "global_load_dwordx4 %22, %25, off offset:1408\n\t"
        "global_load_dwordx4 %23, %25, off offset:1472\n\t"
        "global_load_dwordx4 %24, %25, off offset:1536"
        : "=&v"(d[0]), "=&v"(d[1]), "=&v"(d[2]), "=&v"(d[3]), "=&v"(d[4]),
          "=&v"(d[5]), "=&v"(d[6]), "=&v"(d[7]), "=&v"(d[8]), "=&v"(d[9]),
          "=&v"(d[10]), "=&v"(d[11]), "=&v"(d[12]), "=&v"(d[13]), "=&v"(d[14]),
          "=&v"(d[15]), "=&v"(d[16]), "=&v"(d[17]), "=&v"(d[18]), "=&v"(d[19]),
          "=&v"(d[20]), "=&v"(d[21]), "=&v"(d[22]), "=&v"(d[23]), "=&v"(d[24])
        : "v"(p)
        : "memory");
}

// 13 h loads + 1 mask load. FAST: sc0 (XCD-L2 coherent). SLOW: sc0 sc1 (device). No wait.
template<bool FAST>
__device__ __forceinline__ void hload13t(const u16* Hrow, const float* maddr,
                                         short8* hf, float& mreg) {
    if constexpr (FAST) {
        asm volatile(
            "global_load_dwordx4 %0,  %14, off sc0\n\t"
            "global_load_dwordx4 %1,  %14, off offset:64 sc0\n\t"
            "global_load_dwordx4 %2,  %14, off offset:128 sc0\n\t"
            "global_load_dwordx4 %3,  %14, off offset:192 sc0\n\t"
            "global_load_dwordx4 %4,  %14, off offset:256 sc0\n\t"
            "global_load_dwordx4 %5,  %14, off offset:320 sc0\n\t"
            "global_load_dwordx4 %6,  %14, off offset:384 sc0\n\t"
            "global_load_dwordx4 %7,  %14, off offset:448 sc0\n\t"
            "global_load_dwordx4 %8,  %14, off offset:512 sc0\n\t"
            "global_load_dwordx4 %9,  %14, off offset:576 sc0\n\t"
            "global_load_dwordx4 %10, %14, off offset:640 sc0\n\t"
            "global_load_dwordx4 %11, %14, off offset:704 sc0\n\t"
            "global_load_dwordx4 %12, %14, off offset:768 sc0\n\t"
            "global_load_dword   %13, %15, off"
            : "=&v"(hf[0]), "=&v"(hf[1]), "=&v"(hf[2]), "=&v"(hf[3]), "=&v"(hf[4]),
              "=&v"(hf[5]), "=&v"(hf[6]), "=&v"(hf[7]), "=&v"(hf[8]), "=&v"(hf[9]),
              "=&v"(hf[10]), "=&v"(hf[11]), "=&v"(hf[12]), "=&v"(mreg)
            : "v"(Hrow), "v"(maddr)
            : "memory");
    } else {
        asm volatile(
            "global_load_dwordx4 %0,  %14, off sc0 sc1\n\t"
            "global_load_dwordx4 %1,  %14, off offset:64 sc0 sc1\n\t"
            "global_load_dwordx4 %2,  %14, off offset:128 sc0 sc1\n\t"
            "global_load_dwordx4 %3,  %14, off offset:192 sc0 sc1\n\t"
            "global_load_dwordx4 %4,  %14, off offset:256 sc0 sc1\n\t"
            "global_load_dwordx4 %5,  %14, off offset:320 sc0 sc1\n\t"
            "global_load_dwordx4 %6,  %14, off offset:384 sc0 sc1\n\t"
            "global_load_dwordx4 %7,  %14, off offset:448 sc0 sc1\n\t"
            "global_load_dwordx4 %8,  %14, off offset:512 sc0 sc1\n\t"
            "global_load_dwordx4 %9,  %14, off offset:576 sc0 sc1\n\t"
            "global_load_dwordx4 %10, %14, off offset:640 sc0 sc1\n\t"
            "global_load_dwordx4 %11, %14, off offset:704 sc0 sc1\n\t"
            "global_load_dwordx4 %12, %14, off offset:768 sc0 sc1\n\t"
            "global_load_dword   %13, %15, off"
            : "=&v"(hf[0]), "=&v"(hf[1]), "=&v"(hf[2]), "=&v"(hf[3]), "=&v"(hf[4]),
              "=&v"(hf[5]), "=&v"(hf[6]), "=&v"(hf[7]), "=&v"(hf[8]), "=&v"(hf[9]),
              "=&v"(hf[10]), "=&v"(hf[11]), "=&v"(hf[12]), "=&v"(mreg)
            : "v"(Hrow), "v"(maddr)
            : "memory");
    }
}

template<bool FAST>
__device__ __forceinline__ void hstore1t(u16* p, u32 v) {
    if constexpr (FAST)
        asm volatile("global_store_dword %0, %1, off" :: "v"(p), "v"(v) : "memory");
    else
        asm volatile("global_store_dword %0, %1, off sc0 sc1" :: "v"(p), "v"(v) : "memory");
}

template<bool FAST>
__device__ __forceinline__ void flagstore_t(int* p, int v) {
    if constexpr (FAST)
        asm volatile("global_store_dword %0, %1, off" :: "v"(p), "v"(v) : "memory");
    else
        __hip_atomic_store(p, v, __ATOMIC_RELAXED, __HIP_MEMORY_SCOPE_AGENT);
}

template<bool FAST>
__device__ __forceinline__ int flagpoll_t(const int* p) {
    if constexpr (FAST) {
        int v;
        asm volatile("global_load_dword %0, %1, off sc0\n\ts_waitcnt vmcnt(0)"
                     : "=v"(v) : "v"(p) : "memory");
        return v;
    } else {
        return __hip_atomic_load(p, __ATOMIC_RELAXED, __HIP_MEMORY_SCOPE_AGENT);
    }
}

// probe helpers
__device__ __forceinline__ int ld_sc0p(const int* p) {
    int v;
    asm volatile("global_load_dword %0, %1, off sc0\n\ts_waitcnt vmcnt(0)"
                 : "=v"(v) : "v"(p) : "memory");
    return v;
}
__device__ __forceinline__ void st_plainp(int* p, int v) {
    asm volatile("global_store_dword %0, %1, off\n\ts_waitcnt vmcnt(0)"
                 :: "v"(p), "v"(v) : "memory");
}

// ---------------- templated main recurrent loop (round-6 body) ----------------
template<bool FAST>
__device__ __forceinline__ void lstm_loop(
    const u16* __restrict__ x_bf, const float* __restrict__ masks,
    u16* __restrict__ h_bf, float* __restrict__ raw,
    int* sfbase, int* myfA, const int* pollp,
    const u16* wfrag, float bval,
    float (*gsm)[16][16], float (*c_lds)[16],
    int dir, int bb, int pl, int tid, int lane, int gate, int l15, int hi, int bi_c)
{
    // ---- prologue: load x for step 0, commit ----
    short8 xc[25];
    {
        const int t0 = dir ? (T_LEN - 1) : 0;
        load_x25(x_bf + (size_t)(t0 * BATCH + bb + l15) * DIN + 8 * hi, xc);
        asm volatile("s_waitcnt vmcnt(0)" ::: "memory");
        __builtin_amdgcn_sched_barrier(0);
    }

    for (int tf = 0; tf < T_LEN; ++tf) {
        const int t = dir ? (T_LEN - 1 - tf) : tf;

        // ---- wait: both wave-flags of all 25 writers >= tf (lane-parallel poll) ----
        if (tf > 0) {
            int v = flagpoll_t<FAST>(pollp);
            while (v < tf) {
                if constexpr (!FAST) __builtin_amdgcn_s_sleep(1);
                v = flagpoll_t<FAST>(pollp);
            }
            asm volatile("s_waitcnt vmcnt(0)" ::: "memory");   // xc architecturally complete
            __builtin_amdgcn_sched_barrier(0);
        }

        // ---- issue h loads + mask, no wait ----
        const u16* Hrow = h_bf + (size_t)((dir * 2 + (tf & 1)) * BATCH + bb + l15) * HSTRIDE + 8 * hi;
        const float* maddr = masks + t * BATCH + bb + bi_c;
        short8 hf[13];
        float mreg;
        hload13t<FAST>(Hrow, maddr, hf, mreg);

        // ---- x part (K = 0..800): xc regs x LDS W, overlaps h-load latency ----
        f32x4 acc = {bval, bval, bval, bval};
#pragma unroll
        for (int kk = 0; kk < 25; ++kk)
            acc = __builtin_amdgcn_mfma_f32_16x16x32_bf16(
                xc[kk], *(const short8*)(wfrag + (size_t)kk * 1536), acc, 0, 0, 0);

        // ---- wait h, then h part (K = 800..1216) ----
        asm volatile("s_waitcnt vmcnt(0)" ::: "memory");
        __builtin_amdgcn_sched_barrier(0);
#pragma unroll
        for (int kk = 0; kk < 13; ++kk)
            acc = __builtin_amdgcn_mfma_f32_16x16x32_bf16(
                hf[kk], *(const short8*)(wfrag + (size_t)(25 + kk) * 1536), acc, 0, 0, 0);

        // ---- gate exchange ----
#pragma unroll
        for (int j = 0; j < 4; ++j) gsm[gate][hi * 4 + j][l15] = acc[j];
        __syncthreads();

        // ---- cell update: waves 0,1 (128 threads), 16 batch x 8 col-pairs ----
        if (tid < 128) {
            const int bi = tid >> 3, cp = (tid & 7) * 2;
            const int bg = bb + bi;
            const float m = mreg;
            float h2[2];
#pragma unroll
            for (int q = 0; q < 2; ++q) {
                const int c = cp + q;
                float ig = sigmoidf_(gsm[0][bi][c]);
                float jg = tanhf(gsm[1][bi][c]);
                float og = sigmoidf_(gsm[2][bi][c]);
                float cold = c_lds[bi][c];
                float cn = m * ((1.f - ig) * cold + ig * jg);
                c_lds[bi][c] = cn;
                h2[q] = m * (tanhf(cn) * og);
            }
            u32 hp = (u32)f2bf(h2[0]) | ((u32)f2bf(h2[1]) << 16);
            u16* hdst = h_bf + (size_t)((dir * 2 + ((tf + 1) & 1)) * BATCH + bg) * HSTRIDE + pl * 16 + cp;
            hstore1t<FAST>(hdst, hp);
            float2 rv = make_float2(h2[0], h2[1]);
            *(float2*)(raw + ((size_t)t * BATCH + bg) * (2 * HID) + dir * HID + pl * 16 + cp) = rv;

            // ---- per-wave drain + signal (no block barrier) ----
            if (tf < T_LEN - 1) {
                asm volatile("s_waitcnt vmcnt(0)" ::: "memory");
                if ((tid & 63) == 0)
                    flagstore_t<FAST>(myfA + (tid >> 6) * 32, tf + 1);
            }
        }

        // ---- prefetch x for next step ----
        if (tf < T_LEN - 1) {
            const int tn = dir ? (T_LEN - 2 - tf) : tf + 1;
            load_x25(x_bf + (size_t)(tn * BATCH + bb + l15) * DIN + 8 * hi, xc);
        }
    }
}

// ---------------- persistent per-layer LSTM ----------------
// 1D grid of 200 blocks; gid = blockIdx%8 (round-robin XCD intent), pl = blockIdx/8.
// Group gid = 25 blocks for one (dir, batch-block). Fast path (plain stores + sc0 loads via
// shared XCD-L2) is enabled ONLY after an empirical coherence probe: arrival barrier (safe
// sc0sc1 atomics) -> 3 rounds of plain-store/sc0-load token pings with tight realtime
// timeouts (exact-match tokens, so poison/stale can't fake a pass) -> consensus through the
// safe channel. Any failure => byte-identical round-6 slow path.
__global__ __launch_bounds__(192, 1) void lstm_persist(
    const u16* __restrict__ x_bf,   // [T*B, DIN]
    const u16* __restrict__ W_bf,   // [2][GATES][WSTRIDE]
    const float* __restrict__ fb_l, // [GATES]
    const float* __restrict__ bb_l, // [GATES]
    const float* __restrict__ masks,// [T*B]
    const float* __restrict__ finit,// [2,HID] (layer slice)
    const float* __restrict__ binit,// [2,HID]
    u16* __restrict__ h_bf,         // [2][2][B][HSTRIDE]
    float* __restrict__ c_end,      // [2][B][HID]
    float* __restrict__ raw,        // [T*B, 2H]
    int* __restrict__ syncL)        // per-layer sync area
{
    const int bidx = blockIdx.x;
    const int gid = bidx & 7;
    const int pl  = bidx >> 3;            // 0..24 h-col block
    const int dir = gid >> 2;
    const int bb  = (gid & 3) * 16;       // batch base
    const int tid = threadIdx.x;
    const int lane = tid & 63, gate = tid >> 6;
    const int l15 = lane & 15, hi = lane >> 4;

    int* sfbase = syncL + (size_t)gid * 50 * 32;
    int* myfA   = sfbase + (pl * 2) * 32;
    const int pollidx = (lane < 25) ? lane * 2 : (lane < 50 ? (lane - 25) * 2 + 1 : 49);
    const int* pollp = sfbase + pollidx * 32;
    int* arrb  = syncL + ARR_OFF + gid * 25 * 32;
    int* tokb  = syncL + TOK_OFF + gid * 25 * 32;
    int* voteb = syncL + VOTE_OFF + gid * 25 * 32;

    __shared__ int mode_sh;

    // ================= coherence probe (before any heavy L2 traffic) =================
    // stage 0: safe arrival barrier
    if (tid == 0)
        __hip_atomic_store(arrb + pl * 32, 1, __ATOMIC_RELAXED, __HIP_MEMORY_SCOPE_AGENT);
    if (tid < 64) {
        const int al = (lane < 25) ? lane : 24;
        while (__hip_atomic_load(arrb + al * 32, __ATOMIC_RELAXED, __HIP_MEMORY_SCOPE_AGENT) == 0)
            __builtin_amdgcn_s_sleep(1);
    }
    __syncthreads();

    // stages 1..3: plain-store / sc0-load token pings, tight timeouts
    bool okAll = true;
    for (int r = 1; r <= 3; ++r) {
        if (tid == 0) st_plainp(tokb + pl * 32, r);
        if (tid < 64) {
            const int tl = (lane < 25) ? lane : 24;
            u64 t0 = __builtin_amdgcn_s_memrealtime();
            const u64 TH = (r == 1) ? 1000 : 300;      // 100MHz ticks: 10us / 3us
            bool seen = false;
            while (true) {
                int v = ld_sc0p(tokb + tl * 32);
                if (__all(v == r)) { seen = true; break; }
                if (__builtin_amdgcn_s_memrealtime() - t0 > TH) break;
            }
            okAll = okAll && seen;
        }
        __syncthreads();
    }
    if (tid == 0)
        __hip_atomic_store(voteb + pl * 32, okAll ? 2 : 1, __ATOMIC_RELAXED, __HIP_MEMORY_SCOPE_AGENT);
    if (tid < 64) {
        const int vl = (lane < 25) ? lane : 24;
        int v;
        do {
            v = __hip_atomic_load(voteb + vl * 32, __ATOMIC_RELAXED, __HIP_MEMORY_SCOPE_AGENT);
            if (v == 0) __builtin_amdgcn_s_sleep(1);
        } while (v == 0);
        if (lane == 0) mode_sh = __all(v == 2) ? 1 : 0;
    }
    __syncthreads();
    const bool fastm = (mode_sh == 1);

    // ================= setup (W to LDS, states) =================
    __shared__ u16 Wlds[NKK * 192 * 8];      // 116,736 B, fragment-major
    __shared__ float gsm[3][16][16];
    __shared__ float c_lds[16][16];

    {
        const u16* Wsrc = W_bf + (size_t)dir * GATES * WSTRIDE;
        const int pr = gate * HID + pl * 16 + l15;
        const int k0 = 8 * hi;
        for (int kk = 0; kk < NKK; ++kk)
            *(short8*)&Wlds[(size_t)(kk * 192 + tid) * 8] =
                *(const short8*)(Wsrc + (size_t)pr * WSTRIDE + kk * 32 + k0);
    }

    const float* init = dir ? binit : finit;
    for (int i = tid; i < 256; i += 192)
        c_lds[i >> 4][i & 15] = init[HID + pl * 16 + (i & 15)];

    const int prow = gate * HID + pl * 16 + l15;
    const float bval = (dir ? bb_l : fb_l)[prow];
    const u16* wfrag = &Wlds[(size_t)tid * 8];
    const int bi_c = (tid >> 3) & 15;

    __syncthreads();

    // ================= main loop =================
    if (fastm)
        lstm_loop<true>(x_bf, masks, h_bf, raw, sfbase, myfA, pollp, wfrag, bval,
                        gsm, c_lds, dir, bb, pl, tid, lane, gate, l15, hi, bi_c);
    else
        lstm_loop<false>(x_bf, masks, h_bf, raw, sfbase, myfA, pollp, wfrag, bval,
                         gsm, c_lds, dir, bb, pl, tid, lane, gate, l15, hi, bi_c);

    // ---- dump final c ----
    if (tid < 128) {
        const int bi = tid >> 3, cp = (tid & 7) * 2;
        const int bg = bb + bi;
        float* cd = c_end + (size_t)(dir * BATCH + bg) * HID + pl * 16 + cp;
        cd[0] = c_lds[bi][cp];
        cd[1] = c_lds[bi][cp + 1];
    }
}

// ---------------- save final h/c states ----------------
__global__ void save_states(const float* __restrict__ raw, const float* __restrict__ c_ws,
                            float* __restrict__ out, int layer) {
    const int n = 2 * BATCH * HID;
    for (int i = blockIdx.x * blockDim.x + threadIdx.x; i < n; i += gridDim.x * blockDim.x) {
        int d = i / (BATCH * HID);
        int rem = i - d * (BATCH * HID);
        int b = rem / HID;
        int k = rem - b * HID;
        int t = d ? 0 : (T_LEN - 1);
        float h = raw[((size_t)t * BATCH + b) * (2 * HID) + d * HID + k];
        size_t base = (size_t)T_LEN * BATCH * (2 * HID);
        size_t idx = ((size_t)(2 * layer + d) * BATCH + b) * HID + k;
        out[base + idx] = h;
        out[base + (size_t)2 * 3 * BATCH * HID + idx] = c_ws[d * (BATCH * HID) + b * HID + k];
    }
}

// ---------------- highway: gates GEMM + fused sigmoid blend ----------------
__global__ __launch_bounds__(256) void highway_gemm(
    const u16* __restrict__ A, const u16* __restrict__ Bw, const float* __restrict__ pb,
    float* __restrict__ Rcur, const float* __restrict__ Iprev)
{
    const int m0 = blockIdx.x * 128;
    const int n0 = blockIdx.y * 128;
    const int tid = threadIdx.x, lane = tid & 63, wave = tid >> 6;
    const int wy = wave >> 1, wx = wave & 1;
    const int l15 = lane & 15, hi = lane >> 4;
    const short8 zero8 = {};

    f32x4 acc[4][4] = {};
    const int arow0 = m0 + wy * 64 + l15;
    const int brow0 = n0 + wx * 64 + l15;

    for (int kk = 0; kk < 25; ++kk) {
        const int k0 = kk * 32 + 8 * hi;
        short8 a[4], b[4];
#pragma unroll
        for (int mf = 0; mf < 4; ++mf)
            a[mf] = *(const short8*)(A + (size_t)(arow0 + mf * 16) * DIN + k0);
#pragma unroll
        for (int nf = 0; nf < 4; ++nf) {
            int br = brow0 + nf * 16;
            b[nf] = (br < DIN) ? *(const short8*)(Bw + (size_t)br * DIN + k0) : zero8;
        }
#pragma unroll
        for (int mf = 0; mf < 4; ++mf)
#pragma unroll
            for (int nf = 0; nf < 4; ++nf)
                acc[mf][nf] = __builtin_amdgcn_mfma_f32_16x16x32_bf16(a[mf], b[nf], acc[mf][nf], 0, 0, 0);
    }

#pragma unroll
    for (int mf = 0; mf < 4; ++mf)
#pragma unroll
        for (int nf = 0; nf < 4; ++nf)
#pragma unroll
            for (int j = 0; j < 4; ++j) {
                int row = m0 + wy * 64 + mf * 16 + hi * 4 + j;
                int col = n0 + wx * 64 + nf * 16 + l15;
                if (col < DIN) {
                    float g = sigmoidf_(acc[mf][nf][j] + pb[col]);
                    size_t off = (size_t)row * DIN + col;
                    Rcur[off] = g * Rcur[off] + (1.f - g) * Iprev[off];
                }
            }
}

// ---------------- host ----------------
extern "C" void kernel_launch(void* const* d_in, const int* in_sizes, int n_in,
                              void* d_out, int out_size, void* d_ws, size_t ws_size,
                              hipStream_t stream) {
    const float* x      = (const float*)d_in[0];
    const float* masks  = (const float*)d_in[1];
    const float* fW     = (const float*)d_in[2];
    const float* fb     = (const float*)d_in[3];
    const float* bW     = (const float*)d_in[4];
    const float* bb     = (const float*)d_in[5];
    const float* f_init = (const float*)d_in[6];
    const float* b_init = (const float*)d_in[7];
    const float* pW     = (const float*)d_in[8];
    const float* pb     = (const float*)d_in[9];
    float* out = (float*)d_out;

    char* ws = (char*)d_ws;
    float* R0   = (float*)(ws + 0);                       // 104,857,600
    float* R1   = (float*)(ws + 104857600);               // 104,857,600
    u16* x_bf   = (u16*)(ws + 209715200);                 //  52,428,800
    u16* W_bf   = (u16*)(ws + 262144000);                 //   5,836,800
    u16* pW_bf  = (u16*)(ws + 267980800);                 //   1,280,000
    u16* h_bf   = (u16*)(ws + 269260800);                 //     229,376 ([2][2][64][448])
    float* c_ws = (float*)(ws + 269490176);               //     204,800
    int* syncb  = (int*)(ws + 269694976);                 //     384,000 (3 x SYNC_INTS x 4)
    const int N_TB = T_LEN * BATCH * DIN;

    hipMemsetAsync(syncb, 0, 3 * SYNC_INTS * sizeof(int), stream);

    for (int layer = 0; layer < 3; ++layer) {
        float* raw = (layer == 0) ? R0 : (layer == 1) ? R1 : out;
        const float* inp_f32 = (layer == 0) ? x : (layer == 1) ? R0 : R1;

        cast_f32_bf16<<<4096, 256, 0, stream>>>(inp_f32, x_bf, N_TB);
        cast_W<<<4096, 256, 0, stream>>>(fW, bW, W_bf, layer);
        init_states<<<(2 * 2 * BATCH * HSTRIDE + 255) / 256, 256, 0, stream>>>(f_init, b_init, h_bf, layer);

        lstm_persist<<<200, 192, 0, stream>>>(
            x_bf, W_bf, fb + layer * GATES, bb + layer * GATES, masks,
            f_init + layer * 2 * HID, b_init + layer * 2 * HID,
            h_bf, c_ws, raw, syncb + layer * SYNC_INTS);

        save_states<<<200, 256, 0, stream>>>(raw, c_ws, out, layer);

        if (layer > 0) {
            cast_f32_bf16<<<4096, 256, 0, stream>>>(raw, x_bf, N_TB);
            cast_f32_bf16<<<2048, 256, 0, stream>>>(pW + (size_t)(layer - 1) * DIN * DIN, pW_bf, DIN * DIN);
            highway_gemm<<<dim3(256, 7), 256, 0, stream>>>(
                x_bf, pW_bf, pb + (layer - 1) * DIN, raw, inp_f32);
        }
    }
}

// Round 12
// 6205.283 us; speedup vs baseline: 7.3505x; 1.0695x over previous
//
#include <hip/hip_runtime.h>

typedef __attribute__((ext_vector_type(8))) short short8;
typedef __attribute__((ext_vector_type(4))) float f32x4;
typedef unsigned short u16;
typedef unsigned int u32;
typedef unsigned long long u64;

#define T_LEN 512
#define BATCH 64
#define HID 400
#define GATES 1200   // 3*HID
#define DIN 800      // layer input width (D == 2H)
#define KTOT 1200    // DIN + HID
#define WSTRIDE 1216 // K padded to 38*32
#define HSTRIDE 416  // HID padded to 13*32
#define NKK 38       // K-slices of 32
#define FLAG_STRIDE 32                          // ints (128B line) per flag
#define FLAGS_PER_LAYER (8 * 50 * FLAG_STRIDE)  // 8 groups x 50 wave-flags

__device__ __forceinline__ u16 f2bf(float f) {
    u32 u = __builtin_bit_cast(u32, f);
    u += 0x7fffu + ((u >> 16) & 1u);
    return (u16)(u >> 16);
}
__device__ __forceinline__ float sigmoidf_(float x) { return 1.f / (1.f + expf(-x)); }

// ---------------- cast kernels ----------------
__global__ void cast_f32_bf16(const float* __restrict__ in, u16* __restrict__ out, int n) {
    for (int i = blockIdx.x * blockDim.x + threadIdx.x; i < n; i += gridDim.x * blockDim.x)
        out[i] = f2bf(in[i]);
}

// W_bf layout: [2][GATES][WSTRIDE], cols >= 1200 zeroed
__global__ void cast_W(const float* __restrict__ fW, const float* __restrict__ bW,
                       u16* __restrict__ W_bf, int layer) {
    const int n = 2 * GATES * WSTRIDE;
    for (int i = blockIdx.x * blockDim.x + threadIdx.x; i < n; i += gridDim.x * blockDim.x) {
        int d = i / (GATES * WSTRIDE);
        int rem = i - d * (GATES * WSTRIDE);
        int r = rem / WSTRIDE;
        int k = rem - r * WSTRIDE;
        const float* src = (d ? bW : fW) + (size_t)layer * GATES * KTOT;
        W_bf[i] = (k < KTOT) ? f2bf(src[(size_t)r * KTOT + k]) : (u16)0;
    }
}

// h_bf: [2 dirs][2 bufs][BATCH][HSTRIDE]; buf0 = h_init, buf1 = 0, pads zeroed
__global__ void init_states(const float* __restrict__ f_init, const float* __restrict__ b_init,
                            u16* __restrict__ h_bf, int layer) {
    const int n = 2 * 2 * BATCH * HSTRIDE;
    for (int i = blockIdx.x * blockDim.x + threadIdx.x; i < n; i += gridDim.x * blockDim.x) {
        int d = i / (2 * BATCH * HSTRIDE);
        int rem = i - d * (2 * BATCH * HSTRIDE);
        int buf = rem / (BATCH * HSTRIDE);
        int rem2 = rem - buf * (BATCH * HSTRIDE);
        int k = rem2 % HSTRIDE;
        const float* src = (d ? b_init : f_init) + layer * 2 * HID;
        h_bf[i] = (k < HID && buf == 0) ? f2bf(src[k]) : (u16)0;
    }
}

// issue 25 plain 16B loads (x for a step), no wait
__device__ __forceinline__ void load_x25(const u16* p, short8* d) {
    asm volatile(
        "global_load_dwordx4 %0,  %25, off\n\t"
        "global_load_dwordx4 %1,  %25, off offset:64\n\t"
        "global_load_dwordx4 %2,  %25, off offset:128\n\t"
        "global_load_dwordx4 %3,  %25, off offset:192\n\t"
        "global_load_dwordx4 %4,  %25, off offset:256\n\t"
        "global_load_dwordx4 %5,  %25, off offset:320\n\t"
        "global_load_dwordx4 %6,  %25, off offset:384\n\t"
        "global_load_dwordx4 %7,  %25, off offset:448\n\t"
        "global_load_dwordx4 %8,  %25, off offset:512\n\t"
        "global_load_dwordx4 %9,  %25, off offset:576\n\t"
        "global_load_dwordx4 %10, %25, off offset:640\n\t"
        "global_load_dwordx4 %11, %25, off offset:704\n\t"
        "global_load_dwordx4 %12, %25, off offset:768\n\t"
        "global_load_dwordx4 %13, %25, off offset:832\n\t"
        "global_load_dwordx4 %14, %25, off offset:896\n\t"
        "global_load_dwordx4 %15, %25, off offset:960\n\t"
        "global_load_dwordx4 %16, %25, off offset:1024\n\t"
        "global_load_dwordx4 %17, %25, off offset:1088\n\t"
        "global_load_dwordx4 %18, %25, off offset:1152\n\t"
        "global_load_dwordx4 %19, %25, off offset:1216\n\t"
        "global_load_dwordx4 %20, %25, off offset:1280\n\t"
        "global_load_dwordx4 %21, %25, off offset:1344\n\t"
        "global_load_dwordx4 %22, %25, off offset:1408\n\t"
        "global_load_dwordx4 %23, %25, off offset:1472\n\t"
        "global_load_dwordx4 %24, %25, off offset:1536"
        : "=&v"(d[0]), "=&v"(d[1]), "=&v"(d[2]), "=&v"(d[3]), "=&v"(d[4]),
          "=&v"(d[5]), "=&v"(d[6]), "=&v"(d[7]), "=&v"(d[8]), "=&v"(d[9]),
          "=&v"(d[10]), "=&v"(d[11]), "=&v"(d[12]), "=&v"(d[13]), "=&v"(d[14]),
          "=&v"(d[15]), "=&v"(d[16]), "=&v"(d[17]), "=&v"(d[18]), "=&v"(d[19]),
          "=&v"(d[20]), "=&v"(d[21]), "=&v"(d[22]), "=&v"(d[23]), "=&v"(d[24])
        : "v"(p)
        : "memory");
}

// ---------------- persistent per-layer LSTM (round-6 champion + 2 surgical cuts) ----------------
// grid dim3(25,4,2), 192 threads (3 waves = gates i,j,o). W in LDS fragment-major
// (identity-staged, conflict-free). x(t) in registers (prefetched end of step t-1, drained
// by next poll's vmcnt(0)). h exchange via sc0/sc1 coherence-point ops.
// Cut 1: producer signals per-wave after vmcnt(1) (h-store ACK only; raw store ACK and the
//        end-of-step __syncthreads are off the critical path).
// Cut 2: reader polls with a 2-deep pipelined flag load (monotonic flags -> overlap safe),
//        halving detect latency.
__global__ __launch_bounds__(192, 1) void lstm_persist(
    const u16* __restrict__ x_bf,   // [T*B, DIN]
    const u16* __restrict__ W_bf,   // [2][GATES][WSTRIDE]
    const float* __restrict__ fb_l, // [GATES]
    const float* __restrict__ bb_l, // [GATES]
    const float* __restrict__ masks,// [T*B]
    const float* __restrict__ finit,// [2,HID] (layer slice)
    const float* __restrict__ binit,// [2,HID]
    u16* __restrict__ h_bf,         // [2][2][B][HSTRIDE]
    float* __restrict__ c_end,      // [2][B][HID]
    float* __restrict__ raw,        // [T*B, 2H]
    int* __restrict__ flagsL)       // [8 groups][50 wave-flags][FLAG_STRIDE]
{
    const int dir = blockIdx.z;
    const int pl  = blockIdx.x;           // 0..24 h-col block
    const int bb  = blockIdx.y * 16;      // batch base
    const int tid = threadIdx.x;
    const int lane = tid & 63, gate = tid >> 6;
    const int l15 = lane & 15, hi = lane >> 4;
    const int gid = dir * 4 + blockIdx.y;

    int* sfbase = flagsL + (size_t)gid * 50 * FLAG_STRIDE;
    int* myflag = sfbase + (pl * 2) * FLAG_STRIDE;     // +wave*FLAG_STRIDE
    const int pollidx = (lane < 25) ? lane * 2 : (lane < 50 ? (lane - 25) * 2 + 1 : 49);
    const int* pollp = sfbase + pollidx * FLAG_STRIDE;

    // fragment-major W: thread tid's kk-th fragment at halves (kk*192+tid)*8
    __shared__ u16 Wlds[NKK * 192 * 8];      // 116,736 B
    __shared__ float gsm[3][16][16];
    __shared__ float c_lds[16][16];

    // ---- preload W slice into LDS (identity per-thread staging), once per layer ----
    {
        const u16* Wsrc = W_bf + (size_t)dir * GATES * WSTRIDE;
        const int pr = gate * HID + pl * 16 + l15;      // this thread's W row
        const int k0 = 8 * hi;
        for (int kk = 0; kk < NKK; ++kk)
            *(short8*)&Wlds[(size_t)(kk * 192 + tid) * 8] =
                *(const short8*)(Wsrc + (size_t)pr * WSTRIDE + kk * 32 + k0);
    }

    const float* init = dir ? binit : finit;
    for (int i = tid; i < 256; i += 192)
        c_lds[i >> 4][i & 15] = init[HID + pl * 16 + (i & 15)];

    const int prow = gate * HID + pl * 16 + l15;
    const float bval = (dir ? bb_l : fb_l)[prow];
    const u16* wfrag = &Wlds[(size_t)tid * 8];      // + kk*1536 halves per slice

    const int bi_c = (tid >> 3) & 15;               // cell-update batch row (clamped for tid>=128)

    __syncthreads();

    // ---- prologue: load x for step 0, commit ----
    short8 xc[25];
    {
        const int t0 = dir ? (T_LEN - 1) : 0;
        load_x25(x_bf + (size_t)(t0 * BATCH + bb + l15) * DIN + 8 * hi, xc);
        asm volatile("s_waitcnt vmcnt(0)" ::: "memory");
        __builtin_amdgcn_sched_barrier(0);
    }

    for (int tf = 0; tf < T_LEN; ++tf) {
        const int t = dir ? (T_LEN - 1 - tf) : tf;

        // ---- wait: all 50 wave-flags >= tf (lane-parallel, 2-deep pipelined poll) ----
        if (tf > 0) {
            int va, vb;
            // first probe: full drain (also commits xc loads + prior stores)
            asm volatile("global_load_dword %0, %1, off sc0 sc1\n\t"
                         "s_waitcnt vmcnt(0)"
                         : "=v"(va) : "v"(pollp) : "memory");
            __builtin_amdgcn_sched_barrier(0);
            if (!__all(va >= tf)) {
                // pipelined: keep one flag load in flight (monotonic -> overlap safe)
                asm volatile("global_load_dword %0, %1, off sc0 sc1"
                             : "=v"(va) : "v"(pollp) : "memory");
                while (true) {
                    asm volatile("global_load_dword %0, %1, off sc0 sc1"
                                 : "=v"(vb) : "v"(pollp) : "memory");
                    asm volatile("s_waitcnt vmcnt(1)" ::: "memory");
                    __builtin_amdgcn_sched_barrier(0);
                    if (__all(va >= tf)) break;
                    asm volatile("global_load_dword %0, %1, off sc0 sc1"
                                 : "=v"(va) : "v"(pollp) : "memory");
                    asm volatile("s_waitcnt vmcnt(1)" ::: "memory");
                    __builtin_amdgcn_sched_barrier(0);
                    if (__all(vb >= tf)) break;
                }
                asm volatile("s_waitcnt vmcnt(0)" ::: "memory");
                __builtin_amdgcn_sched_barrier(0);
            }
        }

        // ---- issue h loads (coherent bypass) + mask (plain), no wait ----
        const u16* Hrow = h_bf + (size_t)((dir * 2 + (tf & 1)) * BATCH + bb + l15) * HSTRIDE + 8 * hi;
        const float* maddr = masks + t * BATCH + bb + bi_c;
        short8 hf[13];
        float mreg;
        asm volatile(
            "global_load_dwordx4 %0,  %14, off sc0 sc1\n\t"
            "global_load_dwordx4 %1,  %14, off offset:64 sc0 sc1\n\t"
            "global_load_dwordx4 %2,  %14, off offset:128 sc0 sc1\n\t"
            "global_load_dwordx4 %3,  %14, off offset:192 sc0 sc1\n\t"
            "global_load_dwordx4 %4,  %14, off offset:256 sc0 sc1\n\t"
            "global_load_dwordx4 %5,  %14, off offset:320 sc0 sc1\n\t"
            "global_load_dwordx4 %6,  %14, off offset:384 sc0 sc1\n\t"
            "global_load_dwordx4 %7,  %14, off offset:448 sc0 sc1\n\t"
            "global_load_dwordx4 %8,  %14, off offset:512 sc0 sc1\n\t"
            "global_load_dwordx4 %9,  %14, off offset:576 sc0 sc1\n\t"
            "global_load_dwordx4 %10, %14, off offset:640 sc0 sc1\n\t"
            "global_load_dwordx4 %11, %14, off offset:704 sc0 sc1\n\t"
            "global_load_dwordx4 %12, %14, off offset:768 sc0 sc1\n\t"
            "global_load_dword   %13, %15, off"
            : "=&v"(hf[0]), "=&v"(hf[1]), "=&v"(hf[2]), "=&v"(hf[3]), "=&v"(hf[4]),
              "=&v"(hf[5]), "=&v"(hf[6]), "=&v"(hf[7]), "=&v"(hf[8]), "=&v"(hf[9]),
              "=&v"(hf[10]), "=&v"(hf[11]), "=&v"(hf[12]), "=&v"(mreg)
            : "v"(Hrow), "v"(maddr)
            : "memory");

        // ---- x part (K = 0..800): xc regs x LDS W, overlaps h-load latency ----
        f32x4 acc = {bval, bval, bval, bval};
#pragma unroll
        for (int kk = 0; kk < 25; ++kk)
            acc = __builtin_amdgcn_mfma_f32_16x16x32_bf16(
                xc[kk], *(const short8*)(wfrag + (size_t)kk * 1536), acc, 0, 0, 0);

        // ---- wait h, then h part (K = 800..1216) ----
        asm volatile("s_waitcnt vmcnt(0)" ::: "memory");
        __builtin_amdgcn_sched_barrier(0);
#pragma unroll
        for (int kk = 0; kk < 13; ++kk)
            acc = __builtin_amdgcn_mfma_f32_16x16x32_bf16(
                hf[kk], *(const short8*)(wfrag + (size_t)(25 + kk) * 1536), acc, 0, 0, 0);

        // ---- gate exchange ----
#pragma unroll
        for (int j = 0; j < 4; ++j) gsm[gate][hi * 4 + j][l15] = acc[j];
        __syncthreads();

        // ---- cell update: waves 0,1 (128 threads), 16 batch x 8 col-pairs ----
        if (tid < 128) {
            const int bi = tid >> 3, cp = (tid & 7) * 2;
            const int bg = bb + bi;
            const float m = mreg;
            float h2[2];
#pragma unroll
            for (int q = 0; q < 2; ++q) {
                const int c = cp + q;
                float ig = sigmoidf_(gsm[0][bi][c]);
                float jg = tanhf(gsm[1][bi][c]);
                float og = sigmoidf_(gsm[2][bi][c]);
                float cold = c_lds[bi][c];
                float cn = m * ((1.f - ig) * cold + ig * jg);
                c_lds[bi][c] = cn;
                h2[q] = m * (tanhf(cn) * og);
            }
            u32 hp = (u32)f2bf(h2[0]) | ((u32)f2bf(h2[1]) << 16);
            u16* hdst = h_bf + (size_t)((dir * 2 + ((tf + 1) & 1)) * BATCH + bg) * HSTRIDE + pl * 16 + cp;
            float2 rv = make_float2(h2[0], h2[1]);
            u64 rp = __builtin_bit_cast(u64, rv);
            float* rdst = raw + ((size_t)t * BATCH + bg) * (2 * HID) + dir * HID + pl * 16 + cp;
            // h store FIRST (oldest), raw second -> vmcnt(1) waits only the h ACK
            asm volatile("global_store_dword %0, %1, off sc0 sc1\n\t"
                         "global_store_dwordx2 %2, %3, off"
                         :: "v"(hdst), "v"(hp), "v"(rdst), "v"(rp)
                         : "memory");
            if (tf < T_LEN - 1) {
                asm volatile("s_waitcnt vmcnt(1)" ::: "memory");
                if ((tid & 63) == 0)
                    __hip_atomic_store(myflag + (tid >> 6) * FLAG_STRIDE, tf + 1,
                                       __ATOMIC_RELAXED, __HIP_MEMORY_SCOPE_AGENT);
            }
        }

        // ---- prefetch x for next step (drained by next poll's vmcnt(0)) ----
        if (tf < T_LEN - 1) {
            const int tn = dir ? (T_LEN - 2 - tf) : tf + 1;
            load_x25(x_bf + (size_t)(tn * BATCH + bb + l15) * DIN + 8 * hi, xc);
        }
    }

    // ---- dump final c ----
    if (tid < 128) {
        const int bi = tid >> 3, cp = (tid & 7) * 2;
        const int bg = bb + bi;
        float* cd = c_end + (size_t)(dir * BATCH + bg) * HID + pl * 16 + cp;
        cd[0] = c_lds[bi][cp];
        cd[1] = c_lds[bi][cp + 1];
    }
}

// ---------------- save final h/c states ----------------
__global__ void save_states(const float* __restrict__ raw, const float* __restrict__ c_ws,
                            float* __restrict__ out, int layer) {
    const int n = 2 * BATCH * HID;
    for (int i = blockIdx.x * blockDim.x + threadIdx.x; i < n; i += gridDim.x * blockDim.x) {
        int d = i / (BATCH * HID);
        int rem = i - d * (BATCH * HID);
        int b = rem / HID;
        int k = rem - b * HID;
        int t = d ? 0 : (T_LEN - 1);
        float h = raw[((size_t)t * BATCH + b) * (2 * HID) + d * HID + k];
        size_t base = (size_t)T_LEN * BATCH * (2 * HID);
        size_t idx = ((size_t)(2 * layer + d) * BATCH + b) * HID + k;
        out[base + idx] = h;
        out[base + (size_t)2 * 3 * BATCH * HID + idx] = c_ws[d * (BATCH * HID) + b * HID + k];
    }
}

// ---------------- highway: gates GEMM + fused sigmoid blend ----------------
__global__ __launch_bounds__(256) void highway_gemm(
    const u16* __restrict__ A, const u16* __restrict__ Bw, const float* __restrict__ pb,
    float* __restrict__ Rcur, const float* __restrict__ Iprev)
{
    const int m0 = blockIdx.x * 128;
    const int n0 = blockIdx.y * 128;
    const int tid = threadIdx.x, lane = tid & 63, wave = tid >> 6;
    const int wy = wave >> 1, wx = wave & 1;
    const int l15 = lane & 15, hi = lane >> 4;
    const short8 zero8 = {};

    f32x4 acc[4][4] = {};
    const int arow0 = m0 + wy * 64 + l15;
    const int brow0 = n0 + wx * 64 + l15;

    for (int kk = 0; kk < 25; ++kk) {
        const int k0 = kk * 32 + 8 * hi;
        short8 a[4], b[4];
#pragma unroll
        for (int mf = 0; mf < 4; ++mf)
            a[mf] = *(const short8*)(A + (size_t)(arow0 + mf * 16) * DIN + k0);
#pragma unroll
        for (int nf = 0; nf < 4; ++nf) {
            int br = brow0 + nf * 16;
            b[nf] = (br < DIN) ? *(const short8*)(Bw + (size_t)br * DIN + k0) : zero8;
        }
#pragma unroll
        for (int mf = 0; mf < 4; ++mf)
#pragma unroll
            for (int nf = 0; nf < 4; ++nf)
                acc[mf][nf] = __builtin_amdgcn_mfma_f32_16x16x32_bf16(a[mf], b[nf], acc[mf][nf], 0, 0, 0);
    }

#pragma unroll
    for (int mf = 0; mf < 4; ++mf)
#pragma unroll
        for (int nf = 0; nf < 4; ++nf)
#pragma unroll
            for (int j = 0; j < 4; ++j) {
                int row = m0 + wy * 64 + mf * 16 + hi * 4 + j;
                int col = n0 + wx * 64 + nf * 16 + l15;
                if (col < DIN) {
                    float g = sigmoidf_(acc[mf][nf][j] + pb[col]);
                    size_t off = (size_t)row * DIN + col;
                    Rcur[off] = g * Rcur[off] + (1.f - g) * Iprev[off];
                }
            }
}

// ---------------- host ----------------
extern "C" void kernel_launch(void* const* d_in, const int* in_sizes, int n_in,
                              void* d_out, int out_size, void* d_ws, size_t ws_size,
                              hipStream_t stream) {
    const float* x      = (const float*)d_in[0];
    const float* masks  = (const float*)d_in[1];
    const float* fW     = (const float*)d_in[2];
    const float* fb     = (const float*)d_in[3];
    const float* bW     = (const float*)d_in[4];
    const float* bb     = (const float*)d_in[5];
    const float* f_init = (const float*)d_in[6];
    const float* b_init = (const float*)d_in[7];
    const float* pW     = (const float*)d_in[8];
    const float* pb     = (const float*)d_in[9];
    float* out = (float*)d_out;

    char* ws = (char*)d_ws;
    float* R0   = (float*)(ws + 0);                       // 104,857,600
    float* R1   = (float*)(ws + 104857600);               // 104,857,600
    u16* x_bf   = (u16*)(ws + 209715200);                 //  52,428,800
    u16* W_bf   = (u16*)(ws + 262144000);                 //   5,836,800
    u16* pW_bf  = (u16*)(ws + 267980800);                 //   1,280,000
    u16* h_bf   = (u16*)(ws + 269260800);                 //     212,992 ([2][2][64][416])
    float* c_ws = (float*)(ws + 269473792);               //     204,800
    int* bar    = (int*)(ws + 269678592);                 //     153,600 (3 x FLAGS_PER_LAYER x 4)
    const int N_TB = T_LEN * BATCH * DIN;

    hipMemsetAsync(bar, 0, 3 * FLAGS_PER_LAYER * sizeof(int), stream);

    for (int layer = 0; layer < 3; ++layer) {
        float* raw = (layer == 0) ? R0 : (layer == 1) ? R1 : out;
        const float* inp_f32 = (layer == 0) ? x : (layer == 1) ? R0 : R1;

        cast_f32_bf16<<<4096, 256, 0, stream>>>(inp_f32, x_bf, N_TB);
        cast_W<<<4096, 256, 0, stream>>>(fW, bW, W_bf, layer);
        init_states<<<(2 * 2 * BATCH * HSTRIDE + 255) / 256, 256, 0, stream>>>(f_init, b_init, h_bf, layer);

        lstm_persist<<<dim3(25, 4, 2), 192, 0, stream>>>(
            x_bf, W_bf, fb + layer * GATES, bb + layer * GATES, masks,
            f_init + layer * 2 * HID, b_init + layer * 2 * HID,
            h_bf, c_ws, raw, bar + layer * FLAGS_PER_LAYER);

        save_states<<<200, 256, 0, stream>>>(raw, c_ws, out, layer);

        if (layer > 0) {
            cast_f32_bf16<<<4096, 256, 0, stream>>>(raw, x_bf, N_TB);
            cast_f32_bf16<<<2048, 256, 0, stream>>>(pW + (size_t)(layer - 1) * DIN * DIN, pW_bf, DIN * DIN);
            highway_gemm<<<dim3(256, 7), 256, 0, stream>>>(
                x_bf, pW_bf, pb + (layer - 1) * DIN, raw, inp_f32);
        }
    }
}